// Round 8
// baseline (21905.701 us; speedup 1.0000x reference)
//
#include <hip/hip_runtime.h>
#include <math.h>

typedef __bf16 bf16;
typedef __attribute__((ext_vector_type(8))) __bf16 bf16x8;
typedef __attribute__((ext_vector_type(4))) float f32x4;

static constexpr int B = 256, L = 512, D = 64, P = 256, H = 512, M = 256, HOR = 9;
static constexpr int G = 2048;
static constexpr int NS0 = 24;   // layer0 K/32 (emb 256 + h0 512)
static constexpr int NS1 = 32;   // layer1 K/32 (h0 512 + h1 512)
static constexpr float EPS = 1e-5f;
static constexpr int LDS_BYTES = 65536 + 16 * 260 * 4;   // A(64K max) + Gs

#define MFMA(a, b, c) __builtin_amdgcn_mfma_f32_16x16x32_bf16((a), (b), (c), 0, 0, 0)

__device__ __forceinline__ float sigmoidf_(float x) { return 1.0f / (1.0f + expf(-x)); }
__device__ __forceinline__ float gelu_exact(float x) {
    return 0.5f * x * (1.0f + erff(x * 0.70710678118654752f));
}

// Device-coherent 16B load (2 x 8B agent-scope relaxed atomics -> sc1: reads
// LLC past stale per-XCD L2, pipelined by normal vmcnt scoreboarding).
__device__ __forceinline__ bf16x8 cload(const bf16* p) {
    union { unsigned long long u[2]; bf16x8 v; } r;
    const unsigned long long* q = (const unsigned long long*)p;
    r.u[0] = __hip_atomic_load(q,     __ATOMIC_RELAXED, __HIP_MEMORY_SCOPE_AGENT);
    r.u[1] = __hip_atomic_load(q + 1, __ATOMIC_RELAXED, __HIP_MEMORY_SCOPE_AGENT);
    return r.v;
}

// ---------------------------------------------------------------------------
// emb = gelu(LN(x@Wp+bp)) -> bf16 hi/lo in FRAG layout:
//   elem[(((t*16 + mg)*8 + S)*64 + kq*16 + m)*8 + e]
// where b = mg*16+m, p = S*32 + kq*8 + e.
// ---------------------------------------------------------------------------
__global__ __launch_bounds__(256) void emb_kernel(
    const float* __restrict__ x, const float* __restrict__ Wp,
    const float* __restrict__ bp, const float* __restrict__ gamma,
    const float* __restrict__ beta, bf16* __restrict__ ehi,
    bf16* __restrict__ elo, int use_elo)
{
    const int row = blockIdx.x;          // b*L + t
    const int b   = row >> 9;
    const int t   = row & (L - 1);
    const int p   = threadIdx.x;
    __shared__ float xs[D];
    __shared__ float red[P];

    if (p < D) xs[p] = x[(size_t)row * D + p];
    __syncthreads();

    float acc = bp[p];
#pragma unroll
    for (int k = 0; k < D; ++k) acc = fmaf(xs[k], Wp[k * P + p], acc);

    red[p] = acc;
    __syncthreads();
    for (int s = 128; s > 0; s >>= 1) { if (p < s) red[p] += red[p + s]; __syncthreads(); }
    const float mu = red[0] * (1.0f / (float)P);
    __syncthreads();
    const float d = acc - mu;
    red[p] = d * d;
    __syncthreads();
    for (int s = 128; s > 0; s >>= 1) { if (p < s) red[p] += red[p + s]; __syncthreads(); }
    const float var = red[0] * (1.0f / (float)P);

    const float v = gelu_exact(gamma[p] * d * rsqrtf(var + EPS) + beta[p]);
    const int mg = b >> 4, m = b & 15;
    const int S = p >> 5, kq = (p >> 3) & 3, e = p & 7;
    const size_t o = ((((size_t)t * 16 + mg) * 8 + S) * 64 + kq * 16 + m) * 8 + e;
    const bf16 hh = (bf16)v;
    ehi[o] = hh;
    if (use_elo) elo[o] = (bf16)(v - (float)hh);
}

// ---------------------------------------------------------------------------
// W prep, frag-linear for 16-wave TN=256 blocks:
//  out[(((ng*NS + S)*16 + wc)*64 + lane)*8 + e] =
//    W[g = (wc>>2)*512 + ng*64 + (wc&3)*16 + (lane&15)][k = S*32 + (lane>>4)*8 + e]
// grid (8, NS, 16), 64 threads.
// ---------------------------------------------------------------------------
__global__ __launch_bounds__(64) void prep_w_frag(
    const float* __restrict__ Wih, const float* __restrict__ Whh, int Kih,
    bf16* __restrict__ hi, bf16* __restrict__ lo)
{
    const int ng = blockIdx.x, S = blockIdx.y, wc = blockIdx.z;
    const int lane = threadIdx.x;
    const int g = (wc >> 2) * 512 + ng * 64 + (wc & 3) * 16 + (lane & 15);
    const int kbase = S * 32 + (lane >> 4) * 8;
    const size_t out = (((size_t)(ng * gridDim.y + S) * 16 + wc) * 64 + lane) * 8;
#pragma unroll
    for (int e = 0; e < 8; ++e) {
        const int k = kbase + e;
        const float v = (k < Kih) ? Wih[(size_t)g * Kih + k]
                                  : Whh[(size_t)g * 512 + (k - Kih)];
        const bf16 h = (bf16)v;
        hi[out + e] = h;
        lo[out + e] = (bf16)(v - (float)h);
    }
}

__global__ __launch_bounds__(256) void prep_bias(
    const float* __restrict__ bih0, const float* __restrict__ bhh0,
    const float* __restrict__ bih1, const float* __restrict__ bhh1,
    float* __restrict__ bsum0, float* __restrict__ bsum1)
{
    const int g = blockIdx.x * 256 + threadIdx.x;   // grid.x = 8
    bsum0[g] = bih0[g] + bhh0[g];
    bsum1[g] = bih1[g] + bhh1[g];
}

// ---------------------------------------------------------------------------
// Persistent recurrence: 256 blocks x 1024 threads (16 waves, 1 block/CU).
// Block = 16 batch rows (mg) x 256 gate cols (ng: 64 j x 4 gates); wave wc
// owns cols wc*16..+16. WEIGHTS LIVE ENTIRELY IN REGISTERS (hi+lo, <=256
// VGPR/lane) -- zero weight memory traffic in the loop. LDS holds only the
// staged A panel (frag layout, 48/64 KB) + Gs. h state stored in frag layout;
// sc1 write-through stores + relaxed 16-block barriers (per mg row-group).
// ---------------------------------------------------------------------------
struct RArgs {
    int use_elo;
    const bf16 *ehi, *elo;                       // frag layout
    const bf16 *W0hif, *W0lof, *W1hif, *W1lof;   // frag-linear
    const float *bsum0, *bsum1;
    bf16 *h0hi[2], *h0lo[2], *h1hi[2], *h1lo[2]; // frag layout
    unsigned int* bar;                           // 16 counters, 256B apart
};

template <int LAYER>
__device__ __forceinline__ void tick_loop(const RArgs& a, int mg, int ng, char* lds)
{
    constexpr int NS = LAYER ? NS1 : NS0;
    constexpr int PASSES = NS / 8;          // 3 or 4
    constexpr int SPLIT = LAYER ? 16 : 8;   // S boundary between A seg0/seg1

    const int tid  = threadIdx.x;
    const int lane = tid & 63, wc = tid >> 6;

    // ---- weights into registers (frag-linear: base + tid*8, stride 8192/S)
    bf16x8 whi[NS], wlo[NS];
    {
        const bf16* wh = (LAYER ? a.W1hif : a.W0hif) + (size_t)ng * NS * 8192 + tid * 8;
        const bf16* wl = (LAYER ? a.W1lof : a.W0lof) + (size_t)ng * NS * 8192 + tid * 8;
#pragma unroll
        for (int S = 0; S < NS; ++S) {
            whi[S] = *(const bf16x8*)(wh + (size_t)S * 8192);
            wlo[S] = *(const bf16x8*)(wl + (size_t)S * 8192);
        }
    }

    // ---- staging decode (tick-invariant): pass p covers frag idx p*1024+tid
    int sH[PASSES], sS[PASSES], sL[PASSES];
#pragma unroll
    for (int p = 0; p < PASSES; ++p) {
        const int idx = p * 1024 + tid;
        sH[p] = (idx >= NS * 64);
        const int f = idx - sH[p] * NS * 64;
        sS[p] = f >> 6;
        sL[p] = f & 63;
    }

    // ---- pointwise ownership (threads 0..511): (m, jj, jj+1)
    const int pm = tid >> 5;
    const int jj = (tid & 31) * 2;
    const int jabs = ng * 64 + jj;
    const float* bs = LAYER ? a.bsum1 : a.bsum0;
    const float bI0 = bs[jabs],        bI1 = bs[jabs + 1];
    const float bF0 = bs[512 + jabs],  bF1 = bs[512 + jabs + 1];
    const float bG0 = bs[1024 + jabs], bG1 = bs[1024 + jabs + 1];
    const float bO0 = bs[1536 + jabs], bO1 = bs[1536 + jabs + 1];
    const int hS = ng * 2 + (jj >> 5);
    const size_t hoff = ((size_t)(mg * 16 + hS) * 64 + ((jj >> 3) & 3) * 16 + pm) * 8 + (jj & 7);
    float c0r = 0.f, c1r = 0.f;

    float* gs = (float*)(lds + 65536);   // [16][260]
    unsigned int* bar = a.bar + mg * 64;

    for (int t = 0; t <= L; ++t) {
        const int p0 = t & 1;
        const bool active = LAYER ? (t >= 1) : (t < L);

        if (active) {
            // ---- stage A panel (one phase): load all, write all, one sync
            const bf16 *a0h, *a0l, *a1h, *a1l;
            if (LAYER == 0) {
                a0h = a.ehi + (size_t)(t * 16 + mg) * 4096;   // emb frag slab
                a0l = a.elo + (size_t)(t * 16 + mg) * 4096;
                a1h = a.h0hi[1 - p0] + mg * 8192;
                a1l = a.h0lo[1 - p0] + mg * 8192;
            } else {
                a0h = a.h0hi[1 - p0] + mg * 8192;             // h0[t-1]
                a0l = a.h0lo[1 - p0] + mg * 8192;
                a1h = a.h1hi[p0] + mg * 8192;                 // h1[t-2]
                a1l = a.h1lo[p0] + mg * 8192;
            }
            bf16x8 sv[PASSES];
#pragma unroll
            for (int p = 0; p < PASSES; ++p) {
                const int S = sS[p], ln = sL[p];
                if (S < SPLIT) {
                    const bf16* src = (sH[p] ? a0l : a0h) + (S * 64 + ln) * 8;
                    if (LAYER == 0) {
                        if (sH[p] && !a.use_elo) {
#pragma unroll
                            for (int i = 0; i < 8; ++i) sv[p][i] = (bf16)0.f;
                        } else sv[p] = *(const bf16x8*)src;   // emb: normal load
                    } else sv[p] = cload(src);                // h0: coherent
                } else {
                    const bf16* src = (sH[p] ? a1l : a1h) + ((S - SPLIT) * 64 + ln) * 8;
                    sv[p] = cload(src);                        // h state: coherent
                }
            }
#pragma unroll
            for (int p = 0; p < PASSES; ++p)
                *(bf16x8*)(lds + (p * 1024 + tid) * 16) = sv[p];
            __syncthreads();

            // ---- MFMA: all-register W, broadcast LDS A
            f32x4 hh = {0.f,0.f,0.f,0.f}, hl = {0.f,0.f,0.f,0.f}, lh = {0.f,0.f,0.f,0.f};
#pragma unroll
            for (int S = 0; S < NS; ++S) {
                const bf16x8 Ahi = *(const bf16x8*)(lds + (S * 64 + lane) * 16);
                const bf16x8 Alo = *(const bf16x8*)(lds + NS * 1024 + (S * 64 + lane) * 16);
                hh = MFMA(Ahi, whi[S], hh);
                hl = MFMA(Ahi, wlo[S], hl);
                lh = MFMA(Alo, whi[S], lh);
            }

            // ---- park gates (C/D: col=lane&15, row=(lane>>4)*4+r); stride 260
#pragma unroll
            for (int r = 0; r < 4; ++r)
                gs[((lane >> 4) * 4 + r) * 260 + wc * 16 + (lane & 15)]
                    = hh[r] + hl[r] + lh[r];
            __syncthreads();

            // ---- fused LSTM cell update; h stored frag-layout, sc1 4B stores
            if (tid < 512) {
                bf16* hwh = LAYER ? a.h1hi[1 - p0] : a.h0hi[p0];
                bf16* hwl = LAYER ? a.h1lo[1 - p0] : a.h0lo[p0];
                float hv0, hv1;
                {
                    const float iraw = gs[pm * 260 + jj]       + bI0;
                    const float fraw = gs[pm * 260 + 64 + jj]  + bF0;
                    const float graw = gs[pm * 260 + 128 + jj] + bG0;
                    const float oraw = gs[pm * 260 + 192 + jj] + bO0;
                    const float cv = sigmoidf_(fraw) * c0r + sigmoidf_(iraw) * tanhf(graw);
                    c0r = cv;
                    hv0 = sigmoidf_(oraw) * tanhf(cv);
                }
                {
                    const float iraw = gs[pm * 260 + jj + 1]       + bI1;
                    const float fraw = gs[pm * 260 + 64 + jj + 1]  + bF1;
                    const float graw = gs[pm * 260 + 128 + jj + 1] + bG1;
                    const float oraw = gs[pm * 260 + 192 + jj + 1] + bO1;
                    const float cv = sigmoidf_(fraw) * c1r + sigmoidf_(iraw) * tanhf(graw);
                    c1r = cv;
                    hv1 = sigmoidf_(oraw) * tanhf(cv);
                }
                union { unsigned int u; bf16 b[2]; } ph, pl;
                ph.b[0] = (bf16)hv0; ph.b[1] = (bf16)hv1;
                pl.b[0] = (bf16)(hv0 - (float)ph.b[0]);
                pl.b[1] = (bf16)(hv1 - (float)ph.b[1]);
                __hip_atomic_store((unsigned int*)(hwh + hoff), ph.u,
                                   __ATOMIC_RELAXED, __HIP_MEMORY_SCOPE_AGENT);
                __hip_atomic_store((unsigned int*)(hwl + hoff), pl.u,
                                   __ATOMIC_RELAXED, __HIP_MEMORY_SCOPE_AGENT);
            }
        }

        // ---- 16-block barrier (row-group mg); zero cache-maintenance ops
        __syncthreads();   // drains vmcnt -> sc1 stores visible at LLC
        if (tid == 0) {
            __hip_atomic_fetch_add(bar, 1u, __ATOMIC_RELAXED, __HIP_MEMORY_SCOPE_AGENT);
            const unsigned int target = 16u * (unsigned)(t + 1);
            while (__hip_atomic_load(bar, __ATOMIC_RELAXED, __HIP_MEMORY_SCOPE_AGENT) < target)
                __builtin_amdgcn_s_sleep(1);
        }
        __syncthreads();
    }
}

__global__ __launch_bounds__(1024) void recurrence_kernel(RArgs a)
{
    extern __shared__ __align__(16) char lds[];
    const int b = blockIdx.x;
    const int layer = b >> 7;
    const int r = b & 127;
    const int mg = r >> 3, ng = r & 7;
    if (layer == 0) tick_loop<0>(a, mg, ng, lds);
    else            tick_loop<1>(a, mg, ng, lds);
}

// ---------------------------------------------------------------------------
// head: per batch row b, j = joint_index[b]; h read from frag layout
// ---------------------------------------------------------------------------
__global__ __launch_bounds__(256) void head_kernel(
    const bf16* __restrict__ h_hi, const bf16* __restrict__ h_lo,
    const int* __restrict__ joint_index,
    const float* __restrict__ Wh1, const float* __restrict__ bh1,
    const float* __restrict__ Wh2, const float* __restrict__ bh2,
    float* __restrict__ out)
{
    const int b = blockIdx.x;
    const int t = threadIdx.x;
    const int j = joint_index[b];
    __shared__ float hs[H];
    __shared__ float zs[M];

    const int mgb = b >> 4, mm = b & 15;
#pragma unroll
    for (int rep = 0; rep < 2; ++rep) {
        const int jx = t + rep * 256;
        const size_t o = ((size_t)(mgb * 16 + (jx >> 5)) * 64 + ((jx >> 3) & 3) * 16 + mm) * 8 + (jx & 7);
        hs[jx] = (float)h_hi[o] + (float)h_lo[o];
    }
    __syncthreads();

    float acc = bh1[j * M + t];
    const float* w = Wh1 + (size_t)j * H * M + t;
#pragma unroll 8
    for (int k = 0; k < H; ++k) acc = fmaf(hs[k], w[(size_t)k * M], acc);

    zs[t] = gelu_exact(acc);
    __syncthreads();

    if (t < HOR) {
        float a = bh2[j * HOR + t];
        const float* w2 = Wh2 + (size_t)j * M * HOR + t;
        for (int mq = 0; mq < M; ++mq) a = fmaf(zs[mq], w2[(size_t)mq * HOR], a);
        out[(size_t)b * HOR + t] = a;
    }
}

// ---------------------------------------------------------------------------
extern "C" void kernel_launch(void* const* d_in, const int* in_sizes, int n_in,
                              void* d_out, int out_size, void* d_ws, size_t ws_size,
                              hipStream_t stream)
{
    const float* x     = (const float*)d_in[0];
    const int*   joint = (const int*)  d_in[1];
    const float* Wp    = (const float*)d_in[2];
    const float* bp    = (const float*)d_in[3];
    const float* gamma = (const float*)d_in[4];
    const float* beta  = (const float*)d_in[5];
    const float* Wih0  = (const float*)d_in[6];
    const float* Whh0  = (const float*)d_in[7];
    const float* bih0  = (const float*)d_in[8];
    const float* bhh0  = (const float*)d_in[9];
    const float* Wih1  = (const float*)d_in[10];
    const float* Whh1  = (const float*)d_in[11];
    const float* bih1  = (const float*)d_in[12];
    const float* bhh1  = (const float*)d_in[13];
    const float* Wh1   = (const float*)d_in[14];
    const float* bh1   = (const float*)d_in[15];
    const float* Wh2   = (const float*)d_in[16];
    const float* bh2   = (const float*)d_in[17];
    float* out = (float*)d_out;

    char* base = (char*)d_ws;
    size_t off = 0;
    auto take = [&](size_t nbytes) -> void* {
        void* p = base + off;
        off = (off + nbytes + 255) & ~(size_t)255;
        return p;
    };

    RArgs a;
    a.W0hif = (bf16*)take((size_t)G * (P + H) * 2);
    a.W0lof = (bf16*)take((size_t)G * (P + H) * 2);
    a.W1hif = (bf16*)take((size_t)G * (2 * H) * 2);
    a.W1lof = (bf16*)take((size_t)G * (2 * H) * 2);
    a.bsum0 = (float*)take(G * 4);
    a.bsum1 = (float*)take(G * 4);

    const size_t states_off = off;
    for (int i = 0; i < 2; ++i) a.h0hi[i] = (bf16*)take((size_t)B * H * 2);
    for (int i = 0; i < 2; ++i) a.h0lo[i] = (bf16*)take((size_t)B * H * 2);
    for (int i = 0; i < 2; ++i) a.h1hi[i] = (bf16*)take((size_t)B * H * 2);
    for (int i = 0; i < 2; ++i) a.h1lo[i] = (bf16*)take((size_t)B * H * 2);
    a.bar = (unsigned int*)take(16 * 256);
    const size_t states_bytes = off - states_off;   // h bufs + bar -> zeroed

    bf16* ehi = (bf16*)take((size_t)L * B * P * 2);
    bf16* elo = (bf16*)take((size_t)L * B * P * 2);
    a.use_elo = (off <= ws_size) ? 1 : 0;
    if (!a.use_elo) elo = ehi;   // never read when use_elo==0 (lo staged as 0)
    a.ehi = ehi; a.elo = elo;

    prep_w_frag<<<dim3(8, NS0, 16), 64, 0, stream>>>(Wih0, Whh0, P,
                                                     (bf16*)a.W0hif, (bf16*)a.W0lof);
    prep_w_frag<<<dim3(8, NS1, 16), 64, 0, stream>>>(Wih1, Whh1, H,
                                                     (bf16*)a.W1hif, (bf16*)a.W1lof);
    prep_bias<<<8, 256, 0, stream>>>(bih0, bhh0, bih1, bhh1,
                                     (float*)a.bsum0, (float*)a.bsum1);
    hipMemsetAsync(base + states_off, 0, states_bytes, stream);
    emb_kernel<<<B * L, 256, 0, stream>>>(x, Wp, bp, gamma, beta, ehi, elo, a.use_elo);

    hipFuncSetAttribute((const void*)recurrence_kernel,
                        hipFuncAttributeMaxDynamicSharedMemorySize, LDS_BYTES);
    void* params[] = { &a };
    hipLaunchCooperativeKernel((void*)recurrence_kernel, dim3(256), dim3(1024),
                               params, LDS_BYTES, stream);

    // final h1 (step 511) written at tick t=512 into buf[1-(512&1)] = buf 1
    head_kernel<<<B, 256, 0, stream>>>(a.h1hi[1], a.h1lo[1], joint, Wh1, bh1, Wh2, bh2, out);
}